// Round 5
// baseline (748.237 us; speedup 1.0000x reference)
//
#include <hip/hip_runtime.h>
#include <hip/hip_bf16.h>
#include <stdint.h>

typedef __attribute__((ext_vector_type(8))) __bf16 bf16x8;
typedef __attribute__((ext_vector_type(8))) unsigned short ushort8;
typedef __attribute__((ext_vector_type(4))) float f32x4;
typedef __attribute__((ext_vector_type(4))) unsigned int u32x4;

#define N_NODES 100000
#define N_EDGES 800000
#define FIN 128
#define FH 512
#define FO 40
#define NCHUNK 391   // ceil(N/256)
#define TWBLKS 352   // (128*512 + 48*512)/256

// workspace byte offsets (16B-aligned where vector loads occur)
#define O_DINV   0ull            // N floats
#define O_CNT    400000ull       // N ints
#define O_ROWPTR 800000ull       // N+1 ints
#define O_CUR    1200016ull      // N ints
#define O_SRC    1600016ull      // E ints   (src sorted by dst)
#define O_DSRC   4800016ull      // E floats (dinv[src] sorted by dst)
#define O_W1T    8000016ull      // 512x128 bf16
#define O_W2T    8131088ull      // 48x512 bf16 (zero-padded cols 40..47)
#define O_H1     8180240ull      // N x 512 bf16
#define O_H2     110580240ull    // N x 40 f32
#define O_PART   126580240ull    // 512 ints

__device__ __forceinline__ unsigned short f2bf(float f) {
  unsigned u = __float_as_uint(f);
  u += 0x7fffu + ((u >> 16) & 1u);           // round-to-nearest-even
  return (unsigned short)(u >> 16);
}

__device__ __forceinline__ float blo(unsigned v) { return __uint_as_float(v << 16); }
__device__ __forceinline__ float bhi(unsigned v) { return __uint_as_float(v & 0xffff0000u); }

// truncating f32x8 -> bf16x8 pack from registers (staging for MFMA A)
__device__ __forceinline__ bf16x8 pack8t(u32x4 a, u32x4 b) {
  u32x4 w;
  w.x = __builtin_amdgcn_perm(a.y, a.x, 0x07060302u);
  w.y = __builtin_amdgcn_perm(a.w, a.z, 0x07060302u);
  w.z = __builtin_amdgcn_perm(b.y, b.x, 0x07060302u);
  w.w = __builtin_amdgcn_perm(b.w, b.z, 0x07060302u);
  return __builtin_bit_cast(bf16x8, w);
}

// ---------------- degree count ----------------

__global__ __launch_bounds__(256) void k_count(const int* __restrict__ dst,
                                               int* __restrict__ cnt) {
  int e = blockIdx.x * 256 + threadIdx.x;
  if (e < N_EDGES) atomicAdd(&cnt[__builtin_nontemporal_load(&dst[e])], 1);
}

// ---------------- scan chunk-local + dinv + weight transposes, fused ----------------

__global__ __launch_bounds__(256) void k_scan1tw(const int* __restrict__ cnt,
                                                 int* __restrict__ rowptr,
                                                 int* __restrict__ partials,
                                                 float* __restrict__ dinv,
                                                 const float* __restrict__ w1,
                                                 const float* __restrict__ w2,
                                                 unsigned short* __restrict__ w1t,
                                                 unsigned short* __restrict__ w2t) {
  int b = blockIdx.x;
  if (b >= NCHUNK) {                         // weight-transpose blocks
    int t = (b - NCHUNK) * 256 + threadIdx.x;
    if (t < FIN * FH) {                      // W1^T: [512c][128k]
      int c = t >> 7, k = t & 127;
      w1t[c * 128 + k] = f2bf(w1[k * FH + c]);
    } else {                                 // W2^T: [48c][512k], pad c>=40
      int u = t - FIN * FH;
      int c = u >> 9, k = u & 511;
      w2t[c * FH + k] = (c < FO) ? f2bf(w2[k * FO + c]) : (unsigned short)0;
    }
    return;
  }
  int t = threadIdx.x, g = b * 256 + t;
  int v = (g < N_NODES) ? cnt[g] : 0;
  if (g < N_NODES) dinv[g] = __frsqrt_rn((float)(v + 1));
  int lane = t & 63, w = t >> 6;
  int sc = v;
#pragma unroll
  for (int off = 1; off < 64; off <<= 1) {
    int u = __shfl_up(sc, off);
    if (lane >= off) sc += u;
  }
  __shared__ int wsum[4];
  if (lane == 63) wsum[w] = sc;
  __syncthreads();
  int add = 0;
  for (int j = 0; j < w; j++) add += wsum[j];
  int incl = sc + add;
  if (g < N_NODES) rowptr[g] = incl - v;     // chunk-local exclusive
  if (t == 255) partials[b] = incl;
}

// ---------------- global scan offsets (scan2 folded in) + cur init ----------------

__global__ __launch_bounds__(256) void k_scan3(int* __restrict__ rowptr,
                                               const int* __restrict__ partials,
                                               int* __restrict__ cur) {
  __shared__ int sbase;
  int t = threadIdx.x;
  int chunk = blockIdx.x;
  if (t < 64) {                              // wave 0: base = sum partials[0..chunk)
    int s = 0;
    for (int j = t; j < chunk; j += 64) s += partials[j];
#pragma unroll
    for (int off = 32; off; off >>= 1) s += __shfl_down(s, off);
    if (t == 0) sbase = s;
  }
  __syncthreads();
  int base = sbase;
  int g = chunk * 256 + t;
  if (g < N_NODES) {
    int v = rowptr[g] + base;
    rowptr[g] = v;
    cur[g] = v;
  } else if (g == N_NODES) {
    rowptr[N_NODES] = N_EDGES;
  }
}

__global__ __launch_bounds__(256) void k_scatter(const int* __restrict__ src,
                                                 const int* __restrict__ dst,
                                                 const float* __restrict__ dinv,
                                                 int* __restrict__ cur,
                                                 int* __restrict__ src_sorted,
                                                 float* __restrict__ dinv_src) {
  int e = blockIdx.x * 256 + threadIdx.x;
  if (e < N_EDGES) {
    int s = __builtin_nontemporal_load(&src[e]);
    int d = __builtin_nontemporal_load(&dst[e]);
    int pos = atomicAdd(&cur[d], 1);
    src_sorted[pos] = s;
    dinv_src[pos] = dinv[s];
  }
}

// ---------------- dropout bits (JAX partitionable threefry, key=42) ----------------

__device__ __forceinline__ unsigned tf_bits(unsigned x0, unsigned x1) {
  const unsigned K0 = 0u, K1 = 42u, K2 = 0x1BD11BDAu ^ 42u;
  x0 += K0; x1 += K1;
#define RND(r) { x0 += x1; x1 = (x1 << (r)) | (x1 >> (32 - (r))); x1 ^= x0; }
  RND(13) RND(15) RND(26) RND(6)
  x0 += K1; x1 += K2 + 1u;
  RND(17) RND(29) RND(16) RND(24)
  x0 += K2; x1 += K0 + 2u;
  RND(13) RND(15) RND(26) RND(6)
  x0 += K0; x1 += K1 + 3u;
  RND(17) RND(29) RND(16) RND(24)
  x0 += K1; x1 += K2 + 4u;
  RND(13) RND(15) RND(26) RND(6)
  x0 += K2; x1 += K0 + 5u;
#undef RND
  return x0 ^ x1;   // partitionable path xor-folds (out0, out1)
}

// ---------------- GEMM1: h1[N,512] = x[N,128] @ W1 (bf16 MFMA) ----------------
// 16x16x32 bf16. A: A[m=lane&15][k=(lane>>4)*8+j]. C/D: col=lane&15, row=(lane>>4)*4+reg.

__global__ __launch_bounds__(256) void k_gemm1(const float* __restrict__ x,
                                               const unsigned short* __restrict__ w1t,
                                               unsigned short* __restrict__ h1) {
  int w = threadIdx.x >> 6;
  int lane = threadIdx.x & 63;
  int m = lane & 15, kg = lane >> 4;
  int r0 = blockIdx.x * 32;                  // 32 rows per block
  int cw = w * 128;                          // 128 cols per wave
  f32x4 acc[2][8];
#pragma unroll
  for (int a = 0; a < 2; a++)
#pragma unroll
    for (int t = 0; t < 8; t++)
#pragma unroll
      for (int r = 0; r < 4; r++) acc[a][t][r] = 0.0f;

  const float* xa0 = x + (size_t)(r0 + m) * FIN + kg * 8;
  const float* xa1 = xa0 + 16 * FIN;
#pragma unroll
  for (int kc = 0; kc < 4; kc++) {
    int kb = kc * 32;
    u32x4 a0l = __builtin_nontemporal_load((const u32x4*)(xa0 + kb));
    u32x4 a0h = __builtin_nontemporal_load((const u32x4*)(xa0 + kb + 4));
    u32x4 a1l = __builtin_nontemporal_load((const u32x4*)(xa1 + kb));
    u32x4 a1h = __builtin_nontemporal_load((const u32x4*)(xa1 + kb + 4));
    bf16x8 a0 = pack8t(a0l, a0h);
    bf16x8 a1 = pack8t(a1l, a1h);
#pragma unroll
    for (int t = 0; t < 8; t++) {
      const unsigned short* bp = w1t + (size_t)(cw + t * 16 + m) * FIN + kb + kg * 8;
      bf16x8 b = __builtin_bit_cast(bf16x8, *(const ushort8*)bp);
      acc[0][t] = __builtin_amdgcn_mfma_f32_16x16x32_bf16(a0, b, acc[0][t], 0, 0, 0);
      acc[1][t] = __builtin_amdgcn_mfma_f32_16x16x32_bf16(a1, b, acc[1][t], 0, 0, 0);
    }
  }
#pragma unroll
  for (int rt = 0; rt < 2; rt++)
#pragma unroll
    for (int t = 0; t < 8; t++)
#pragma unroll
      for (int r = 0; r < 4; r++) {
        int row = r0 + rt * 16 + kg * 4 + r;
        int col = cw + t * 16 + m;
        h1[(size_t)row * FH + col] = f2bf(acc[rt][t][r]);
      }
}

// ---------------- aggregate L1 half-columns + bias + relu + dropout -> hidden ----------------
// two passes over edges; pass p covers channels [256p, 256p+256).
// one wave per node; lane owns 4 contiguous channels. Working set h1-half = 51 MB
// stays LLC-resident alongside the 102 MB hidden write stream (vs 102+205 thrash).

__global__ __launch_bounds__(256) void k_agg1(const unsigned short* __restrict__ h1,
                                              const int* __restrict__ rowptr,
                                              const int* __restrict__ src_sorted,
                                              const float* __restrict__ dinv_src,
                                              const float* __restrict__ dinv,
                                              const float* __restrict__ b1,
                                              float* __restrict__ hidden,
                                              int pass) {
  int i = blockIdx.x * 4 + (threadIdx.x >> 6);
  int lane = threadIdx.x & 63;
  int rs = rowptr[i], re = rowptr[i + 1];
  float di = dinv[i];
  int c = (pass << 8) + (lane << 2);         // 4 channels per lane

  // dropout mask bits for my 4 channels (bit j set = DROP)
  unsigned flat = (unsigned)i * FH + (unsigned)c;
  unsigned mb = 0;
#pragma unroll
  for (int j = 0; j < 4; j++) mb |= (tf_bits(0u, flat + j) >> 31) << j;

  float a0 = 0, a1 = 0, a2 = 0, a3 = 0;

  for (int base = rs; base < re; base += 64) {
    int n = re - base; if (n > 64) n = 64;
    int myi = 0; float myw = 0.0f;
    if (lane < n) {
      myi = src_sorted[base + lane];
      myw = dinv_src[base + lane];
    }
    int j = 0;
    for (; j + 4 <= n; j += 4) {             // 4 gathers in flight
      int s0 = __shfl(myi, j),     s1 = __shfl(myi, j + 1);
      int s2 = __shfl(myi, j + 2), s3 = __shfl(myi, j + 3);
      float w0 = __shfl(myw, j),     w1_ = __shfl(myw, j + 1);
      float w2_ = __shfl(myw, j + 2), w3_ = __shfl(myw, j + 3);
      uint2 v0 = *(const uint2*)(h1 + (((unsigned)s0 << 9) | c));
      uint2 v1 = *(const uint2*)(h1 + (((unsigned)s1 << 9) | c));
      uint2 v2 = *(const uint2*)(h1 + (((unsigned)s2 << 9) | c));
      uint2 v3 = *(const uint2*)(h1 + (((unsigned)s3 << 9) | c));
      a0 += w0 * blo(v0.x); a1 += w0 * bhi(v0.x); a2 += w0 * blo(v0.y); a3 += w0 * bhi(v0.y);
      a0 += w1_ * blo(v1.x); a1 += w1_ * bhi(v1.x); a2 += w1_ * blo(v1.y); a3 += w1_ * bhi(v1.y);
      a0 += w2_ * blo(v2.x); a1 += w2_ * bhi(v2.x); a2 += w2_ * blo(v2.y); a3 += w2_ * bhi(v2.y);
      a0 += w3_ * blo(v3.x); a1 += w3_ * bhi(v3.x); a2 += w3_ * blo(v3.y); a3 += w3_ * bhi(v3.y);
    }
    for (; j < n; j++) {
      int s0 = __shfl(myi, j);
      float w0 = __shfl(myw, j);
      uint2 v0 = *(const uint2*)(h1 + (((unsigned)s0 << 9) | c));
      a0 += w0 * blo(v0.x); a1 += w0 * bhi(v0.x); a2 += w0 * blo(v0.y); a3 += w0 * bhi(v0.y);
    }
  }
  { // self loop, weight di
    uint2 vs = *(const uint2*)(h1 + (((unsigned)i << 9) | c));
    a0 += di * blo(vs.x); a1 += di * bhi(vs.x); a2 += di * blo(vs.y); a3 += di * bhi(vs.y);
  }

  float4 bb = *(const float4*)(b1 + c);
  f32x4 o;
  o[0] = (mb & 1u) ? 0.0f : fmaxf(a0 * di + bb.x, 0.0f) * 2.0f;
  o[1] = (mb & 2u) ? 0.0f : fmaxf(a1 * di + bb.y, 0.0f) * 2.0f;
  o[2] = (mb & 4u) ? 0.0f : fmaxf(a2 * di + bb.z, 0.0f) * 2.0f;
  o[3] = (mb & 8u) ? 0.0f : fmaxf(a3 * di + bb.w, 0.0f) * 2.0f;
  *(f32x4*)(hidden + (size_t)i * FH + c) = o;
}

// ---------------- GEMM2: h2[N,40] = hidden[N,512] @ W2 (bf16 MFMA, cols padded 48) ----------------

__global__ __launch_bounds__(256) void k_gemm2(const float* __restrict__ hidden,
                                               const unsigned short* __restrict__ w2t,
                                               float* __restrict__ h2) {
  int wid = blockIdx.x * 4 + (threadIdx.x >> 6);
  if (wid >= N_NODES / 16) return;
  int lane = threadIdx.x & 63;
  int m = lane & 15, kg = lane >> 4;
  int r0 = wid * 16;
  f32x4 acc[3];
#pragma unroll
  for (int t = 0; t < 3; t++)
#pragma unroll
    for (int r = 0; r < 4; r++) acc[t][r] = 0.0f;

  const float* ap = hidden + (size_t)(r0 + m) * FH + kg * 8;
#pragma unroll 8
  for (int kc = 0; kc < 16; kc++) {
    int kb = kc * 32;
    u32x4 al = __builtin_nontemporal_load((const u32x4*)(ap + kb));
    u32x4 ah = __builtin_nontemporal_load((const u32x4*)(ap + kb + 4));
    bf16x8 a = pack8t(al, ah);
#pragma unroll
    for (int t = 0; t < 3; t++) {
      bf16x8 b = __builtin_bit_cast(bf16x8,
          *(const ushort8*)(w2t + (size_t)(t * 16 + m) * FH + kb + kg * 8));
      acc[t] = __builtin_amdgcn_mfma_f32_16x16x32_bf16(a, b, acc[t], 0, 0, 0);
    }
  }
#pragma unroll
  for (int t = 0; t < 3; t++)
#pragma unroll
    for (int r = 0; r < 4; r++) {
      int row = r0 + kg * 4 + r;
      int col = t * 16 + m;
      if (col < FO) h2[(size_t)row * FO + col] = acc[t][r];
    }
}

// ---------------- aggregate L2 + bias -> out (f32) ----------------

__global__ __launch_bounds__(256) void k_agg2(const float* __restrict__ h2,
                                              const int* __restrict__ rowptr,
                                              const int* __restrict__ src_sorted,
                                              const float* __restrict__ dinv_src,
                                              const float* __restrict__ dinv,
                                              const float* __restrict__ b2,
                                              float* __restrict__ out) {
  int i = blockIdx.x * 4 + (threadIdx.x >> 6);
  int lane = threadIdx.x & 63;
  int rs = rowptr[i], re = rowptr[i + 1];
  float di = dinv[i];
  float acc = 0.0f;

  for (int base = rs; base < re; base += 64) {
    int n = re - base; if (n > 64) n = 64;
    int myi = 0; float myw = 0.0f;
    if (lane < n) {
      myi = __builtin_nontemporal_load(&src_sorted[base + lane]);
      myw = __builtin_nontemporal_load(&dinv_src[base + lane]);
    }
    for (int j = 0; j < n; j++) {
      int s = __shfl(myi, j);
      float wgt = __shfl(myw, j);
      if (lane < FO) acc += wgt * h2[(size_t)s * FO + lane];
    }
  }
  if (lane < FO) {
    acc += di * h2[(size_t)i * FO + lane];
    out[(size_t)i * FO + lane] = acc * di + b2[lane];
  }
}

// ---------------- launcher ----------------

extern "C" void kernel_launch(void* const* d_in, const int* in_sizes, int n_in,
                              void* d_out, int out_size, void* d_ws, size_t ws_size,
                              hipStream_t stream) {
  const float* x  = (const float*)d_in[0];
  const int* ei   = (const int*)d_in[1];
  const float* w1 = (const float*)d_in[2];
  const float* b1 = (const float*)d_in[3];
  const float* w2 = (const float*)d_in[4];
  const float* b2 = (const float*)d_in[5];

  char* ws = (char*)d_ws;
  float* dinv            = (float*)(ws + O_DINV);
  int* cnt               = (int*)(ws + O_CNT);
  int* rowptr            = (int*)(ws + O_ROWPTR);
  int* cur               = (int*)(ws + O_CUR);
  int* src_sorted        = (int*)(ws + O_SRC);
  float* dinv_src        = (float*)(ws + O_DSRC);
  unsigned short* w1t    = (unsigned short*)(ws + O_W1T);
  unsigned short* w2t    = (unsigned short*)(ws + O_W2T);
  unsigned short* h1     = (unsigned short*)(ws + O_H1);
  float* h2              = (float*)(ws + O_H2);
  int* partials          = (int*)(ws + O_PART);

  float* outp   = (float*)d_out;                       // [N,40]
  float* hidden = outp + (size_t)N_NODES * FO;         // [N,512]

  const int* srcA = ei;             // edge_index[0]
  const int* dstA = ei + N_EDGES;   // edge_index[1]

  hipMemsetAsync(cnt, 0, N_NODES * sizeof(int), stream);
  k_count<<<(N_EDGES + 255) / 256, 256, 0, stream>>>(dstA, cnt);
  k_scan1tw<<<NCHUNK + TWBLKS, 256, 0, stream>>>(cnt, rowptr, partials, dinv,
                                                 w1, w2, w1t, w2t);
  k_scan3<<<NCHUNK, 256, 0, stream>>>(rowptr, partials, cur);
  k_scatter<<<(N_EDGES + 255) / 256, 256, 0, stream>>>(srcA, dstA, dinv, cur,
                                                       src_sorted, dinv_src);
  k_gemm1<<<N_NODES / 32, 256, 0, stream>>>(x, w1t, h1);
  k_agg1<<<N_NODES / 4, 256, 0, stream>>>(h1, rowptr, src_sorted, dinv_src, dinv,
                                          b1, hidden, 0);
  k_agg1<<<N_NODES / 4, 256, 0, stream>>>(h1, rowptr, src_sorted, dinv_src, dinv,
                                          b1, hidden, 1);
  k_gemm2<<<(N_NODES / 16 + 3) / 4, 256, 0, stream>>>(hidden, w2t, h2);
  k_agg2<<<N_NODES / 4, 256, 0, stream>>>(h2, rowptr, src_sorted, dinv_src, dinv,
                                          b2, outp);
}

// Round 6
// 656.982 us; speedup vs baseline: 1.1389x; 1.1389x over previous
//
#include <hip/hip_runtime.h>
#include <hip/hip_bf16.h>
#include <stdint.h>

typedef __attribute__((ext_vector_type(8))) __bf16 bf16x8;
typedef __attribute__((ext_vector_type(8))) unsigned short ushort8;
typedef __attribute__((ext_vector_type(4))) float f32x4;
typedef __attribute__((ext_vector_type(4))) unsigned int u32x4;

#define N_NODES 100000
#define N_EDGES 800000
#define FIN 128
#define FH 512
#define FO 40
#define NCHUNK 391   // ceil(N/256)
#define TWBLKS 352   // (128*512 + 48*512)/256

// workspace byte offsets (16B-aligned where vector loads occur)
#define O_DINV   0ull            // N floats
#define O_CNT    400000ull       // N ints
#define O_ROWPTR 800000ull       // N+1 ints
#define O_CUR    1200016ull      // N ints
#define O_SRC    1600016ull      // E ints   (src sorted by dst)
#define O_DSRC   4800016ull      // E floats (dinv[src] sorted by dst)
#define O_W1T    8000016ull      // 512x128 bf16
#define O_W2T    8131088ull      // 48x512 bf16 (zero-padded cols 40..47)
#define O_AXG    8180240ull      // N x 128 f32  (aggregated x)
#define O_H2     59380240ull     // N x 40 f32
#define O_PART   75380240ull     // 512 ints

__device__ __forceinline__ unsigned short f2bf(float f) {
  unsigned u = __float_as_uint(f);
  u += 0x7fffu + ((u >> 16) & 1u);           // round-to-nearest-even
  return (unsigned short)(u >> 16);
}

// truncating f32x8 -> bf16x8 pack from registers (staging for MFMA A)
__device__ __forceinline__ bf16x8 pack8t(u32x4 a, u32x4 b) {
  u32x4 w;
  w.x = __builtin_amdgcn_perm(a.y, a.x, 0x07060302u);
  w.y = __builtin_amdgcn_perm(a.w, a.z, 0x07060302u);
  w.z = __builtin_amdgcn_perm(b.y, b.x, 0x07060302u);
  w.w = __builtin_amdgcn_perm(b.w, b.z, 0x07060302u);
  return __builtin_bit_cast(bf16x8, w);
}

// ---------------- degree count ----------------

__global__ __launch_bounds__(256) void k_count(const int* __restrict__ dst,
                                               int* __restrict__ cnt) {
  int e = blockIdx.x * 256 + threadIdx.x;
  if (e < N_EDGES) atomicAdd(&cnt[__builtin_nontemporal_load(&dst[e])], 1);
}

// ---------------- scan chunk-local + dinv + weight transposes, fused ----------------

__global__ __launch_bounds__(256) void k_scan1tw(const int* __restrict__ cnt,
                                                 int* __restrict__ rowptr,
                                                 int* __restrict__ partials,
                                                 float* __restrict__ dinv,
                                                 const float* __restrict__ w1,
                                                 const float* __restrict__ w2,
                                                 unsigned short* __restrict__ w1t,
                                                 unsigned short* __restrict__ w2t) {
  int b = blockIdx.x;
  if (b >= NCHUNK) {                         // weight-transpose blocks
    int t = (b - NCHUNK) * 256 + threadIdx.x;
    if (t < FIN * FH) {                      // W1^T: [512c][128k]
      int c = t >> 7, k = t & 127;
      w1t[c * 128 + k] = f2bf(w1[k * FH + c]);
    } else {                                 // W2^T: [48c][512k], pad c>=40
      int u = t - FIN * FH;
      int c = u >> 9, k = u & 511;
      w2t[c * FH + k] = (c < FO) ? f2bf(w2[k * FO + c]) : (unsigned short)0;
    }
    return;
  }
  int t = threadIdx.x, g = b * 256 + t;
  int v = (g < N_NODES) ? cnt[g] : 0;
  if (g < N_NODES) dinv[g] = __frsqrt_rn((float)(v + 1));
  int lane = t & 63, w = t >> 6;
  int sc = v;
#pragma unroll
  for (int off = 1; off < 64; off <<= 1) {
    int u = __shfl_up(sc, off);
    if (lane >= off) sc += u;
  }
  __shared__ int wsum[4];
  if (lane == 63) wsum[w] = sc;
  __syncthreads();
  int add = 0;
  for (int j = 0; j < w; j++) add += wsum[j];
  int incl = sc + add;
  if (g < N_NODES) rowptr[g] = incl - v;     // chunk-local exclusive
  if (t == 255) partials[b] = incl;
}

// ---------------- global scan offsets + cur init ----------------

__global__ __launch_bounds__(256) void k_scan3(int* __restrict__ rowptr,
                                               const int* __restrict__ partials,
                                               int* __restrict__ cur) {
  __shared__ int sbase;
  int t = threadIdx.x;
  int chunk = blockIdx.x;
  if (t < 64) {                              // wave 0: base = sum partials[0..chunk)
    int s = 0;
    for (int j = t; j < chunk; j += 64) s += partials[j];
#pragma unroll
    for (int off = 32; off; off >>= 1) s += __shfl_down(s, off);
    if (t == 0) sbase = s;
  }
  __syncthreads();
  int base = sbase;
  int g = chunk * 256 + t;
  if (g < N_NODES) {
    int v = rowptr[g] + base;
    rowptr[g] = v;
    cur[g] = v;
  } else if (g == N_NODES) {
    rowptr[N_NODES] = N_EDGES;
  }
}

__global__ __launch_bounds__(256) void k_scatter(const int* __restrict__ src,
                                                 const int* __restrict__ dst,
                                                 const float* __restrict__ dinv,
                                                 int* __restrict__ cur,
                                                 int* __restrict__ src_sorted,
                                                 float* __restrict__ dinv_src) {
  int e = blockIdx.x * 256 + threadIdx.x;
  if (e < N_EDGES) {
    int s = __builtin_nontemporal_load(&src[e]);
    int d = __builtin_nontemporal_load(&dst[e]);
    int pos = atomicAdd(&cur[d], 1);
    src_sorted[pos] = s;
    dinv_src[pos] = dinv[s];
  }
}

// ---------------- dropout bits (JAX partitionable threefry, key=42) ----------------

__device__ __forceinline__ unsigned tf_bits(unsigned x0, unsigned x1) {
  const unsigned K0 = 0u, K1 = 42u, K2 = 0x1BD11BDAu ^ 42u;
  x0 += K0; x1 += K1;
#define RND(r) { x0 += x1; x1 = (x1 << (r)) | (x1 >> (32 - (r))); x1 ^= x0; }
  RND(13) RND(15) RND(26) RND(6)
  x0 += K1; x1 += K2 + 1u;
  RND(17) RND(29) RND(16) RND(24)
  x0 += K2; x1 += K0 + 2u;
  RND(13) RND(15) RND(26) RND(6)
  x0 += K0; x1 += K1 + 3u;
  RND(17) RND(29) RND(16) RND(24)
  x0 += K1; x1 += K2 + 4u;
  RND(13) RND(15) RND(26) RND(6)
  x0 += K2; x1 += K0 + 5u;
#undef RND
  return x0 ^ x1;   // partitionable path xor-folds (out0, out1)
}

// ---------------- aggregate x (128-dim, BEFORE gemm1): axg = D^-1/2 (A+I) D^-1/2 x ----
// Commuted vs reference: (A (X W1)) == (A X) W1 exactly. Gather rows are 512 B
// from a 51 MB array -> LLC-resident. One wave per node; lane owns 2 channels.

__global__ __launch_bounds__(256) void k_aggx(const float* __restrict__ x,
                                              const int* __restrict__ rowptr,
                                              const int* __restrict__ src_sorted,
                                              const float* __restrict__ dinv_src,
                                              const float* __restrict__ dinv,
                                              float* __restrict__ axg) {
  int i = blockIdx.x * 4 + (threadIdx.x >> 6);
  int lane = threadIdx.x & 63;
  int rs = rowptr[i], re = rowptr[i + 1];
  float di = dinv[i];
  int c = lane << 1;                         // 2 channels per lane

  float a0 = 0.0f, a1 = 0.0f;

  for (int base = rs; base < re; base += 64) {
    int n = re - base; if (n > 64) n = 64;
    int myi = 0; float myw = 0.0f;
    if (lane < n) {
      myi = src_sorted[base + lane];
      myw = dinv_src[base + lane];
    }
    int j = 0;
    for (; j + 4 <= n; j += 4) {             // 4 gathers in flight
      int s0 = __shfl(myi, j),     s1 = __shfl(myi, j + 1);
      int s2 = __shfl(myi, j + 2), s3 = __shfl(myi, j + 3);
      float w0 = __shfl(myw, j),      w1_ = __shfl(myw, j + 1);
      float w2_ = __shfl(myw, j + 2), w3_ = __shfl(myw, j + 3);
      float2 v0 = *(const float2*)(x + (((size_t)s0 << 7) | c));
      float2 v1 = *(const float2*)(x + (((size_t)s1 << 7) | c));
      float2 v2 = *(const float2*)(x + (((size_t)s2 << 7) | c));
      float2 v3 = *(const float2*)(x + (((size_t)s3 << 7) | c));
      a0 += w0 * v0.x + w1_ * v1.x + w2_ * v2.x + w3_ * v3.x;
      a1 += w0 * v0.y + w1_ * v1.y + w2_ * v2.y + w3_ * v3.y;
    }
    for (; j < n; j++) {
      int s0 = __shfl(myi, j);
      float w0 = __shfl(myw, j);
      float2 v0 = *(const float2*)(x + (((size_t)s0 << 7) | c));
      a0 += w0 * v0.x; a1 += w0 * v0.y;
    }
  }
  { // self loop, weight di
    float2 vs = *(const float2*)(x + (((size_t)i << 7) | c));
    a0 += di * vs.x; a1 += di * vs.y;
  }
  float2 o; o.x = a0 * di; o.y = a1 * di;
  *(float2*)(axg + (((size_t)i << 7) | c)) = o;
}

// ---------------- GEMM1 fused: hidden = dropout(relu(axg @ W1 + b1)) ----------------
// 16x16x32 bf16 MFMA. A: A[m=lane&15][k=(lane>>4)*8+j]. C/D: col=lane&15, row=(lane>>4)*4+reg.

__global__ __launch_bounds__(256) void k_gemm1f(const float* __restrict__ axg,
                                                const unsigned short* __restrict__ w1t,
                                                const float* __restrict__ b1,
                                                float* __restrict__ hidden) {
  int w = threadIdx.x >> 6;
  int lane = threadIdx.x & 63;
  int m = lane & 15, kg = lane >> 4;
  int r0 = blockIdx.x * 32;                  // 32 rows per block
  int cw = w * 128;                          // 128 cols per wave
  f32x4 acc[2][8];
#pragma unroll
  for (int a = 0; a < 2; a++)
#pragma unroll
    for (int t = 0; t < 8; t++)
#pragma unroll
      for (int r = 0; r < 4; r++) acc[a][t][r] = 0.0f;

  const float* xa0 = axg + (size_t)(r0 + m) * FIN + kg * 8;
  const float* xa1 = xa0 + 16 * FIN;
#pragma unroll
  for (int kc = 0; kc < 4; kc++) {
    int kb = kc * 32;
    u32x4 a0l = *(const u32x4*)(xa0 + kb);
    u32x4 a0h = *(const u32x4*)(xa0 + kb + 4);
    u32x4 a1l = *(const u32x4*)(xa1 + kb);
    u32x4 a1h = *(const u32x4*)(xa1 + kb + 4);
    bf16x8 a0 = pack8t(a0l, a0h);
    bf16x8 a1 = pack8t(a1l, a1h);
#pragma unroll
    for (int t = 0; t < 8; t++) {
      const unsigned short* bp = w1t + (size_t)(cw + t * 16 + m) * FIN + kb + kg * 8;
      bf16x8 b = __builtin_bit_cast(bf16x8, *(const ushort8*)bp);
      acc[0][t] = __builtin_amdgcn_mfma_f32_16x16x32_bf16(a0, b, acc[0][t], 0, 0, 0);
      acc[1][t] = __builtin_amdgcn_mfma_f32_16x16x32_bf16(a1, b, acc[1][t], 0, 0, 0);
    }
  }

  float bcol[8];
#pragma unroll
  for (int t = 0; t < 8; t++) bcol[t] = b1[cw + t * 16 + m];

#pragma unroll
  for (int rt = 0; rt < 2; rt++)
#pragma unroll
    for (int t = 0; t < 8; t++)
#pragma unroll
      for (int r = 0; r < 4; r++) {
        int row = r0 + rt * 16 + kg * 4 + r;
        int col = cw + t * 16 + m;
        unsigned flat = (unsigned)row * FH + (unsigned)col;
        float v = fmaxf(acc[rt][t][r] + bcol[t], 0.0f);
        v = (tf_bits(0u, flat) >> 31) ? 0.0f : v * 2.0f;
        hidden[flat] = v;
      }
}

// ---------------- GEMM2: h2[N,40] = hidden[N,512] @ W2 (bf16 MFMA, cols padded 48) ----------------

__global__ __launch_bounds__(256) void k_gemm2(const float* __restrict__ hidden,
                                               const unsigned short* __restrict__ w2t,
                                               float* __restrict__ h2) {
  int wid = blockIdx.x * 4 + (threadIdx.x >> 6);
  if (wid >= N_NODES / 16) return;
  int lane = threadIdx.x & 63;
  int m = lane & 15, kg = lane >> 4;
  int r0 = wid * 16;
  f32x4 acc[3];
#pragma unroll
  for (int t = 0; t < 3; t++)
#pragma unroll
    for (int r = 0; r < 4; r++) acc[t][r] = 0.0f;

  const float* ap = hidden + (size_t)(r0 + m) * FH + kg * 8;
#pragma unroll 8
  for (int kc = 0; kc < 16; kc++) {
    int kb = kc * 32;
    u32x4 al = __builtin_nontemporal_load((const u32x4*)(ap + kb));
    u32x4 ah = __builtin_nontemporal_load((const u32x4*)(ap + kb + 4));
    bf16x8 a = pack8t(al, ah);
#pragma unroll
    for (int t = 0; t < 3; t++) {
      bf16x8 b = __builtin_bit_cast(bf16x8,
          *(const ushort8*)(w2t + (size_t)(t * 16 + m) * FH + kb + kg * 8));
      acc[t] = __builtin_amdgcn_mfma_f32_16x16x32_bf16(a, b, acc[t], 0, 0, 0);
    }
  }
#pragma unroll
  for (int t = 0; t < 3; t++)
#pragma unroll
    for (int r = 0; r < 4; r++) {
      int row = r0 + kg * 4 + r;
      int col = t * 16 + m;
      if (col < FO) h2[(size_t)row * FO + col] = acc[t][r];
    }
}

// ---------------- aggregate L2 + bias -> out (f32); h2 = 16 MB, LLC-resident ----------------

__global__ __launch_bounds__(256) void k_agg2(const float* __restrict__ h2,
                                              const int* __restrict__ rowptr,
                                              const int* __restrict__ src_sorted,
                                              const float* __restrict__ dinv_src,
                                              const float* __restrict__ dinv,
                                              const float* __restrict__ b2,
                                              float* __restrict__ out) {
  int i = blockIdx.x * 4 + (threadIdx.x >> 6);
  int lane = threadIdx.x & 63;
  int rs = rowptr[i], re = rowptr[i + 1];
  float di = dinv[i];
  float acc = 0.0f;

  for (int base = rs; base < re; base += 64) {
    int n = re - base; if (n > 64) n = 64;
    int myi = 0; float myw = 0.0f;
    if (lane < n) {
      myi = __builtin_nontemporal_load(&src_sorted[base + lane]);
      myw = __builtin_nontemporal_load(&dinv_src[base + lane]);
    }
    for (int j = 0; j < n; j++) {
      int s = __shfl(myi, j);
      float wgt = __shfl(myw, j);
      if (lane < FO) acc += wgt * h2[(size_t)s * FO + lane];
    }
  }
  if (lane < FO) {
    acc += di * h2[(size_t)i * FO + lane];
    out[(size_t)i * FO + lane] = acc * di + b2[lane];
  }
}

// ---------------- launcher ----------------

extern "C" void kernel_launch(void* const* d_in, const int* in_sizes, int n_in,
                              void* d_out, int out_size, void* d_ws, size_t ws_size,
                              hipStream_t stream) {
  const float* x  = (const float*)d_in[0];
  const int* ei   = (const int*)d_in[1];
  const float* w1 = (const float*)d_in[2];
  const float* b1 = (const float*)d_in[3];
  const float* w2 = (const float*)d_in[4];
  const float* b2 = (const float*)d_in[5];

  char* ws = (char*)d_ws;
  float* dinv            = (float*)(ws + O_DINV);
  int* cnt               = (int*)(ws + O_CNT);
  int* rowptr            = (int*)(ws + O_ROWPTR);
  int* cur               = (int*)(ws + O_CUR);
  int* src_sorted        = (int*)(ws + O_SRC);
  float* dinv_src        = (float*)(ws + O_DSRC);
  unsigned short* w1t    = (unsigned short*)(ws + O_W1T);
  unsigned short* w2t    = (unsigned short*)(ws + O_W2T);
  float* axg             = (float*)(ws + O_AXG);
  float* h2              = (float*)(ws + O_H2);
  int* partials          = (int*)(ws + O_PART);

  float* outp   = (float*)d_out;                       // [N,40]
  float* hidden = outp + (size_t)N_NODES * FO;         // [N,512]

  const int* srcA = ei;             // edge_index[0]
  const int* dstA = ei + N_EDGES;   // edge_index[1]

  hipMemsetAsync(cnt, 0, N_NODES * sizeof(int), stream);
  k_count<<<(N_EDGES + 255) / 256, 256, 0, stream>>>(dstA, cnt);
  k_scan1tw<<<NCHUNK + TWBLKS, 256, 0, stream>>>(cnt, rowptr, partials, dinv,
                                                 w1, w2, w1t, w2t);
  k_scan3<<<NCHUNK, 256, 0, stream>>>(rowptr, partials, cur);
  k_scatter<<<(N_EDGES + 255) / 256, 256, 0, stream>>>(srcA, dstA, dinv, cur,
                                                       src_sorted, dinv_src);
  k_aggx<<<N_NODES / 4, 256, 0, stream>>>(x, rowptr, src_sorted, dinv_src, dinv, axg);
  k_gemm1f<<<N_NODES / 32, 256, 0, stream>>>(axg, w1t, b1, hidden);
  k_gemm2<<<(N_NODES / 16 + 3) / 4, 256, 0, stream>>>(hidden, w2t, h2);
  k_agg2<<<N_NODES / 4, 256, 0, stream>>>(h2, rowptr, src_sorted, dinv_src, dinv,
                                          b2, outp);
}